// Round 11
// baseline (478.360 us; speedup 1.0000x reference)
//
#include <hip/hip_runtime.h>
#include <hip/hip_fp16.h>
#include <math.h>

// GCN 3-layer: h = relu(Agg(x@W1)+b1); h = relu(Agg(h@W2)+b2); out = Agg(h@W3)+b3
// Weight-free aggregation: gemm epilogue writes H'[r] = dinv[r]*(XW)[r] (fp16),
// then out[i] = dinv_i*(H'_i + sum_{j in N(i)} H'_j) + b.  CSR stores src only
// (4 B/edge); padding slots point to zeroed sentinel row N.
// fill_edges: 4 dst-windowed passes (live scatter region fits per-XCD L2).
// GEMM: MFMA fp16 hi/lo split, LDS-staged swizzled A tile, 2 A-fragments/wave
// (48 MFMA per chunk per wave), fragment-packed W.
// agg: whole wave per node - 4 edge-slot quarters x 16 feature lanes,
// shfl_xor reduction; no intra-wave divergence.

#define N_NODES 100000
#define N_EDGES 1600000

typedef _Float16 f16x8 __attribute__((ext_vector_type(8)));
typedef float    f32x4 __attribute__((ext_vector_type(4)));

// ---------------- preprocessing ----------------

__global__ __launch_bounds__(256) void k_zero_int(int* __restrict__ p, int n) {
    int i = blockIdx.x * 256 + threadIdx.x;
    if (i < n) p[i] = 0;
}

__global__ __launch_bounds__(256) void k_count(const int* __restrict__ dst, int* __restrict__ cnt, int E) {
    int e = blockIdx.x * 256 + threadIdx.x;
    if (e < E) atomicAdd(&cnt[dst[e]], 1);
}

// per-256-block exclusive scan (over 8-padded counts) + block sums
__global__ __launch_bounds__(256) void k_scan_block(const int* __restrict__ cnt, int* __restrict__ excl,
                                                    int* __restrict__ bsum, int n) {
    __shared__ int s[256];
    int i = blockIdx.x * 256 + threadIdx.x;
    int v = (i < n) ? ((cnt[i] + 7) & ~7) : 0;   // padded segment length
    s[threadIdx.x] = v;
    __syncthreads();
    #pragma unroll
    for (int off = 1; off < 256; off <<= 1) {
        int t = (threadIdx.x >= (unsigned)off) ? s[threadIdx.x - off] : 0;
        __syncthreads();
        s[threadIdx.x] += t;
        __syncthreads();
    }
    if (i < n) excl[i] = s[threadIdx.x] - v;
    if (threadIdx.x == 255) bsum[blockIdx.x] = s[255];
}

__global__ __launch_bounds__(512) void k_scan_partials(int* __restrict__ bsum, int nb) {
    __shared__ int s[512];
    int tid = threadIdx.x;
    int v = (tid < nb) ? bsum[tid] : 0;
    s[tid] = v;
    __syncthreads();
    #pragma unroll
    for (int off = 1; off < 512; off <<= 1) {
        int t = (tid >= (unsigned)off) ? s[tid - off] : 0;
        __syncthreads();
        s[tid] += t;
        __syncthreads();
    }
    if (tid < nb) bsum[tid] = s[tid] - v;   // exclusive
}

__global__ __launch_bounds__(256) void k_finalize(const int* __restrict__ excl, const int* __restrict__ bsum,
                                                  const int* __restrict__ cnt, int* __restrict__ rowptr,
                                                  int* __restrict__ fill, float* __restrict__ dinv, int n) {
    int i = blockIdx.x * 256 + threadIdx.x;
    if (i < n) {
        int rp = excl[i] + bsum[i >> 8];
        rowptr[i] = rp;     // 8-aligned
        fill[i]   = rp;
        dinv[i]   = rsqrtf((float)(cnt[i] + 1));
    }
}

// init csr to sentinel N (zero row) and zero the sentinel activation row
__global__ __launch_bounds__(256) void k_init_csr(int* __restrict__ csr, int n, unsigned int* __restrict__ phz) {
    int i = blockIdx.x * 256 + threadIdx.x;
    if (i < n) csr[i] = N_NODES;
    if (blockIdx.x == 0 && threadIdx.x < 64) phz[threadIdx.x] = 0;   // 256 B = row N of H'
}

// dst-windowed scatter: live csr write region per pass stays L2-resident
__global__ __launch_bounds__(256) void k_fill_edges(const int* __restrict__ src, const int* __restrict__ dst,
                                                    int* __restrict__ fill, int* __restrict__ csr,
                                                    int E, int lo, int hi) {
    int e = blockIdx.x * 256 + threadIdx.x;
    if (e < E) {
        int d = dst[e];
        if (d >= lo && d < hi) {
            int p = atomicAdd(&fill[d], 1);
            csr[p] = src[e];
        }
    }
}

// W pack: fragment-order layout so GEMM B-loads are lane-contiguous.
__global__ __launch_bounds__(256) void k_wpack(const float* __restrict__ W, _Float16* __restrict__ Wpk, int K) {
    int j = blockIdx.x * 256 + threadIdx.x;
    if (j < K * 128) {
        int i  = j & 7;
        int l  = (j >> 3) & 63;
        int tc = (j >> 9) & 7;
        int c  = j >> 12;
        int col = tc * 16 + (l & 15);
        int k   = c * 32 + (l >> 4) * 8 + i;
        float w = W[(size_t)k * 128 + col];
        _Float16 h = (_Float16)w;
        Wpk[j] = h;
        Wpk[(size_t)K * 128 + j] = (_Float16)(w - (float)h);
    }
}

// ---------------- MFMA GEMM: Y[n,128] = dinv * (X[n,K] @ W[K,128]), fp16 out ----
// 4 waves/block, 128 rows/block, 2 A-fragments (32 rows) per wave -> 48 MFMA
// per chunk per wave against one set of B loads.  A staged through LDS with
// col4-XOR swizzle; next chunk prefetched to regs across the barrier.

template <int K>
__global__ __launch_bounds__(256) void k_gemm_mfma(const float* __restrict__ X,
                                                   const _Float16* __restrict__ Wpk,
                                                   const float* __restrict__ dinv,
                                                   _Float16* __restrict__ Y, int n) {
    constexpr int NC = K / 32;
    __shared__ float sX[128 * 32];           // 16 KB, float4-slot = r*8 + g (swizzled)
    const int t    = threadIdx.x;
    const int wave = t >> 6;
    const int lane = t & 63;
    const int lrow = lane & 15;
    const int kgrp = lane >> 4;              // 0..3
    const int row0 = blockIdx.x * 128;
    const int R0   = wave * 32 + lrow;       // LDS row, fragment 0
    const int R1   = R0 + 16;                // fragment 1
    const _Float16* __restrict__ Wlo = Wpk + (size_t)K * 128;

    // staging: thread t covers float4-slots t, t+256, t+512, t+768
    const int gs  = t & 7;
    const int rsb = t >> 3;                  // 0..31
    const float* __restrict__ xr0 = X + (size_t)(row0 + rsb)      * K;
    const float* __restrict__ xr1 = X + (size_t)(row0 + rsb + 32) * K;
    const float* __restrict__ xr2 = X + (size_t)(row0 + rsb + 64) * K;
    const float* __restrict__ xr3 = X + (size_t)(row0 + rsb + 96) * K;
    const bool ok0 = row0 + rsb      < n;
    const bool ok1 = row0 + rsb + 32 < n;
    const bool ok2 = row0 + rsb + 64 < n;
    const bool ok3 = row0 + rsb + 96 < n;
    const int gc0 = (gs ^ ( rsb       & 7)) << 2;
    const int gc1 = (gs ^ ((rsb + 32) & 7)) << 2;
    const int gc2 = (gs ^ ((rsb + 64) & 7)) << 2;
    const int gc3 = (gs ^ ((rsb + 96) & 7)) << 2;

    f32x4 acc0[8], acc1[8];
    #pragma unroll
    for (int i = 0; i < 8; ++i) {
        acc0[i] = (f32x4){0.f, 0.f, 0.f, 0.f};
        acc1[i] = (f32x4){0.f, 0.f, 0.f, 0.f};
    }

    const float4 z4 = make_float4(0.f, 0.f, 0.f, 0.f);
    float4 rv0 = ok0 ? *(const float4*)&xr0[gc0] : z4;
    float4 rv1 = ok1 ? *(const float4*)&xr1[gc1] : z4;
    float4 rv2 = ok2 ? *(const float4*)&xr2[gc2] : z4;
    float4 rv3 = ok3 ? *(const float4*)&xr3[gc3] : z4;
    *(float4*)&sX[((rsb     ) * 8 + gs) * 4] = rv0;
    *(float4*)&sX[((rsb + 32) * 8 + gs) * 4] = rv1;
    *(float4*)&sX[((rsb + 64) * 8 + gs) * 4] = rv2;
    *(float4*)&sX[((rsb + 96) * 8 + gs) * 4] = rv3;
    __syncthreads();

    #pragma unroll
    for (int c = 0; c < NC; ++c) {
        if (c + 1 < NC) {   // prefetch next chunk to regs
            rv0 = ok0 ? *(const float4*)&xr0[(c + 1) * 32 + gc0] : z4;
            rv1 = ok1 ? *(const float4*)&xr1[(c + 1) * 32 + gc1] : z4;
            rv2 = ok2 ? *(const float4*)&xr2[(c + 1) * 32 + gc2] : z4;
            rv3 = ok3 ? *(const float4*)&xr3[(c + 1) * 32 + gc3] : z4;
        }
        // A fragments from LDS (swizzled)
        float4 x0a = *(const float4*)&sX[(R0 * 8 + ((kgrp * 2)     ^ (R0 & 7))) * 4];
        float4 x0b = *(const float4*)&sX[(R0 * 8 + ((kgrp * 2 + 1) ^ (R0 & 7))) * 4];
        float4 x1a = *(const float4*)&sX[(R1 * 8 + ((kgrp * 2)     ^ (R1 & 7))) * 4];
        float4 x1b = *(const float4*)&sX[(R1 * 8 + ((kgrp * 2 + 1) ^ (R1 & 7))) * 4];
        float xs0[8] = {x0a.x, x0a.y, x0a.z, x0a.w, x0b.x, x0b.y, x0b.z, x0b.w};
        float xs1[8] = {x1a.x, x1a.y, x1a.z, x1a.w, x1b.x, x1b.y, x1b.z, x1b.w};
        f16x8 ah0, al0, ah1, al1;
        #pragma unroll
        for (int i = 0; i < 8; ++i) {
            _Float16 h0 = (_Float16)xs0[i];
            ah0[i] = h0;
            al0[i] = (_Float16)(xs0[i] - (float)h0);
            _Float16 h1 = (_Float16)xs1[i];
            ah1[i] = h1;
            al1[i] = (_Float16)(xs1[i] - (float)h1);
        }
        const size_t wb = ((size_t)(c * 8) * 64 + lane) * 8;
        #pragma unroll
        for (int tc = 0; tc < 8; ++tc) {
            f16x8 bh = *(const f16x8*)(Wpk + wb + (size_t)tc * 512);
            f16x8 bl = *(const f16x8*)(Wlo + wb + (size_t)tc * 512);
            acc0[tc] = __builtin_amdgcn_mfma_f32_16x16x32_f16(ah0, bh, acc0[tc], 0, 0, 0);
            acc0[tc] = __builtin_amdgcn_mfma_f32_16x16x32_f16(al0, bh, acc0[tc], 0, 0, 0);
            acc0[tc] = __builtin_amdgcn_mfma_f32_16x16x32_f16(ah0, bl, acc0[tc], 0, 0, 0);
            acc1[tc] = __builtin_amdgcn_mfma_f32_16x16x32_f16(ah1, bh, acc1[tc], 0, 0, 0);
            acc1[tc] = __builtin_amdgcn_mfma_f32_16x16x32_f16(al1, bh, acc1[tc], 0, 0, 0);
            acc1[tc] = __builtin_amdgcn_mfma_f32_16x16x32_f16(ah1, bl, acc1[tc], 0, 0, 0);
        }
        if (c + 1 < NC) {
            __syncthreads();
            *(float4*)&sX[((rsb     ) * 8 + gs) * 4] = rv0;
            *(float4*)&sX[((rsb + 32) * 8 + gs) * 4] = rv1;
            *(float4*)&sX[((rsb + 64) * 8 + gs) * 4] = rv2;
            *(float4*)&sX[((rsb + 96) * 8 + gs) * 4] = rv3;
            __syncthreads();
        }
    }

    // epilogue: prescale by dinv -> fp16 (fragment 0 then fragment 1)
    #pragma unroll
    for (int r = 0; r < 4; ++r) {
        int grow = row0 + wave * 32 + kgrp * 4 + r;
        if (grow < n) {
            float dv = dinv[grow];
            _Float16* yr = Y + (size_t)grow * 128 + lrow;
            #pragma unroll
            for (int tc = 0; tc < 8; ++tc) yr[tc * 16] = (_Float16)(dv * acc0[tc][r]);
        }
    }
    #pragma unroll
    for (int r = 0; r < 4; ++r) {
        int grow = row0 + wave * 32 + 16 + kgrp * 4 + r;
        if (grow < n) {
            float dv = dinv[grow];
            _Float16* yr = Y + (size_t)grow * 128 + lrow;
            #pragma unroll
            for (int tc = 0; tc < 8; ++tc) yr[tc * 16] = (_Float16)(dv * acc1[tc][r]);
        }
    }
}

// ---------------- aggregation (+ bias, + optional relu) ----------------
// ONE node per wave: quarter-wave q (4 groups) gathers edges e+2q, e+2q+1;
// 16 feature lanes x uint4 cover the 256 B row.  After the edge loop an
// 8-value shfl_xor(16/32) reduction merges the 4 quarter partials.
// No intra-wave divergence (cn uniform per wave).

__device__ __forceinline__ void acc8(float a[8], uint4 u) {
    float2 p;
    p = __half22float2(*(__half2*)&u.x); a[0] += p.x; a[1] += p.y;
    p = __half22float2(*(__half2*)&u.y); a[2] += p.x; a[3] += p.y;
    p = __half22float2(*(__half2*)&u.z); a[4] += p.x; a[5] += p.y;
    p = __half22float2(*(__half2*)&u.w); a[6] += p.x; a[7] += p.y;
}

template <bool RELU>
__global__ __launch_bounds__(256) void k_agg(const __half* __restrict__ H, const int* __restrict__ rowptr,
                                             const int* __restrict__ cnt, const int* __restrict__ csr,
                                             const float* __restrict__ dinv, const float* __restrict__ bias,
                                             float* __restrict__ out, int n) {
    const int lane  = threadIdx.x & 63;
    const int q     = lane >> 4;   // edge-slot quarter
    const int fl    = lane & 15;   // features 8*fl .. 8*fl+7
    const int wave0 = (int)((blockIdx.x * 256 + threadIdx.x) >> 6);
    const int nwave = (int)((gridDim.x * 256) >> 6);
    const uint4* __restrict__ Hu = (const uint4*)H;   // 16 uint4 per row

    for (int node = wave0; node < n; node += nwave) {
        float a[8] = {0.f, 0.f, 0.f, 0.f, 0.f, 0.f, 0.f, 0.f};
        if (q == 0) {   // self term, counted once
            uint4 u = Hu[(size_t)node * 16 + fl];
            float2 p;
            p = __half22float2(*(__half2*)&u.x); a[0] = p.x; a[1] = p.y;
            p = __half22float2(*(__half2*)&u.y); a[2] = p.x; a[3] = p.y;
            p = __half22float2(*(__half2*)&u.z); a[4] = p.x; a[5] = p.y;
            p = __half22float2(*(__half2*)&u.w); a[6] = p.x; a[7] = p.y;
        }

        const int c0 = rowptr[node];
        const int cn = cnt[node];
        #pragma unroll 2
        for (int e = 0; e < cn; e += 8) {
            int2 id = *(const int2*)&csr[c0 + e + 2 * q];   // 8B aligned
            uint4 u0 = Hu[(size_t)id.x * 16 + fl];
            uint4 u1 = Hu[(size_t)id.y * 16 + fl];
            acc8(a, u0);
            acc8(a, u1);
        }

        // merge quarter partials: lanes differing in bits 4,5
        #pragma unroll
        for (int i = 0; i < 8; ++i) {
            a[i] += __shfl_xor(a[i], 16);
            a[i] += __shfl_xor(a[i], 32);
        }

        if (q == 0) {
            const float dv = dinv[node];
            const float4 b0 = *(const float4*)&bias[fl * 8];
            const float4 b1 = *(const float4*)&bias[fl * 8 + 4];
            float4 o0, o1;
            o0.x = fmaf(dv, a[0], b0.x); o0.y = fmaf(dv, a[1], b0.y);
            o0.z = fmaf(dv, a[2], b0.z); o0.w = fmaf(dv, a[3], b0.w);
            o1.x = fmaf(dv, a[4], b1.x); o1.y = fmaf(dv, a[5], b1.y);
            o1.z = fmaf(dv, a[6], b1.z); o1.w = fmaf(dv, a[7], b1.w);
            if (RELU) {
                o0.x = fmaxf(o0.x, 0.f); o0.y = fmaxf(o0.y, 0.f);
                o0.z = fmaxf(o0.z, 0.f); o0.w = fmaxf(o0.w, 0.f);
                o1.x = fmaxf(o1.x, 0.f); o1.y = fmaxf(o1.y, 0.f);
                o1.z = fmaxf(o1.z, 0.f); o1.w = fmaxf(o1.w, 0.f);
            }
            *(float4*)&out[(size_t)node * 128 + fl * 8]     = o0;
            *(float4*)&out[(size_t)node * 128 + fl * 8 + 4] = o1;
        }
    }
}

// ---------------- launch ----------------

extern "C" void kernel_launch(void* const* d_in, const int* in_sizes, int n_in,
                              void* d_out, int out_size, void* d_ws, size_t ws_size,
                              hipStream_t stream) {
    const float* x  = (const float*)d_in[0];
    const int*   ei = (const int*)d_in[1];
    const float* W1 = (const float*)d_in[2];
    const float* b1 = (const float*)d_in[3];
    const float* W2 = (const float*)d_in[4];
    const float* b2 = (const float*)d_in[5];
    const float* W3 = (const float*)d_in[6];
    const float* b3 = (const float*)d_in[7];
    float* out = (float*)d_out;

    const int N = N_NODES, E = N_EDGES;
    const int EP = E + 7 * N + 64;   // padded CSR capacity (4 B entries)
    const int* src = ei;       // edge_index[0]
    const int* dst = ei + E;   // edge_index[1]

    char* w = (char*)d_ws;
    auto alloc = [&](size_t bytes) -> void* {
        void* p = (void*)w;
        w += (bytes + 255) & ~(size_t)255;
        return p;
    };
    int*      cnt    = (int*)alloc((size_t)N * 4);
    int*      excl   = (int*)alloc((size_t)N * 4);
    int*      bsum   = (int*)alloc(4096);
    int*      rowptr = (int*)alloc((size_t)N * 4);
    int*      fill   = (int*)alloc((size_t)N * 4);
    float*    dinv   = (float*)alloc((size_t)N * 4);
    int*      csr    = (int*)alloc((size_t)EP * 4);
    _Float16* Ph     = (_Float16*)alloc((size_t)(N + 8) * 128 * 2);  // fp16 H' + sentinel row N
    _Float16* Wpk    = (_Float16*)alloc((size_t)2 * 256 * 128 * 2);  // packed split weights
    float*    Q      = out;  // f32 ping-pong through d_out; rewritten by final layer

    const int nbN = (N + 255) / 256;
    const int nbE = (E + 255) / 256;
    const int nbP = (EP + 255) / 256;

    // CSR build (8-padded segments; padding -> sentinel row N of H', kept zero)
    k_zero_int<<<nbN, 256, 0, stream>>>(cnt, N);
    k_count<<<nbE, 256, 0, stream>>>(dst, cnt, E);
    k_scan_block<<<nbN, 256, 0, stream>>>(cnt, excl, bsum, N);
    k_scan_partials<<<1, 512, 0, stream>>>(bsum, nbN);
    k_finalize<<<nbN, 256, 0, stream>>>(excl, bsum, cnt, rowptr, fill, dinv, N);
    k_init_csr<<<nbP, 256, 0, stream>>>(csr, EP, (unsigned int*)(Ph + (size_t)N * 128));
    // dst-windowed scatter: 4 passes, live csr region per-XCD-L2-resident
    for (int r = 0; r < 4; ++r) {
        int lo = r * (N / 4);
        int hi = (r == 3) ? N : (r + 1) * (N / 4);
        k_fill_edges<<<nbE, 256, 0, stream>>>(src, dst, fill, csr, E, lo, hi);
    }

    const int gemm_grid = (N + 127) / 128;   // 782
    const int agg_grid  = 2048;

    // layer 1
    k_wpack<<<(256 * 128 + 255) / 256, 256, 0, stream>>>(W1, Wpk, 256);
    k_gemm_mfma<256><<<gemm_grid, 256, 0, stream>>>(x, Wpk, dinv, Ph, N);
    k_agg<true><<<agg_grid, 256, 0, stream>>>((const __half*)Ph, rowptr, cnt, csr, dinv, b1, Q, N);
    // layer 2
    k_wpack<<<(128 * 128 + 255) / 256, 256, 0, stream>>>(W2, Wpk, 128);
    k_gemm_mfma<128><<<gemm_grid, 256, 0, stream>>>(Q, Wpk, dinv, Ph, N);
    k_agg<true><<<agg_grid, 256, 0, stream>>>((const __half*)Ph, rowptr, cnt, csr, dinv, b2, Q, N);
    // layer 3
    k_wpack<<<(128 * 128 + 255) / 256, 256, 0, stream>>>(W3, Wpk, 128);
    k_gemm_mfma<128><<<gemm_grid, 256, 0, stream>>>(Q, Wpk, dinv, Ph, N);
    k_agg<false><<<agg_grid, 256, 0, stream>>>((const __half*)Ph, rowptr, cnt, csr, dinv, b3, out, N);
}